// Round 1
// baseline (659.832 us; speedup 1.0000x reference)
//
#include <hip/hip_runtime.h>
#include <hip/hip_bf16.h>

#define MDIM  128
#define FEAT  8256      // 128*129/2
#define HID   1651
#define HIDP  1664      // 13*128, zero-padded
#define BATCH 4096
#define BK    64

using f32x4  = __attribute__((ext_vector_type(4))) float;
using bf16x8 = __attribute__((ext_vector_type(8))) __bf16;

__device__ __forceinline__ void gload_lds16(const void* g, void* l) {
    __builtin_amdgcn_global_load_lds(
        (const __attribute__((address_space(1))) void*)g,
        (__attribute__((address_space(3))) void*)l,
        16, 0, 0);
}

// ---------------------------------------------------------------------------
// Kernel 1: gather triu(sim) -> X bf16 [BATCH, FEAT]
// grid: (ceil(FEAT/256), BATCH), block 256
// ---------------------------------------------------------------------------
__global__ void pack_x_kernel(const float* __restrict__ sim,
                              __hip_bfloat16* __restrict__ X) {
    const int f = blockIdx.x * 256 + threadIdx.x;
    const int b = blockIdx.y;
    if (f >= FEAT) return;
    // row i such that off(i) = i*(257-i)/2 <= f < off(i+1)
    float ff = (float)f;
    int i = (int)((257.0f - sqrtf(66049.0f - 8.0f * ff)) * 0.5f);
    if (i < 0) i = 0;
    if (i > 127) i = 127;
    while (i < 127 && ((i + 1) * (257 - (i + 1))) / 2 <= f) ++i;
    while (i > 0 && (i * (257 - i)) / 2 > f) --i;
    const int off = (i * (257 - i)) / 2;
    const int j = i + (f - off);
    const float v = sim[(long long)b * (MDIM * MDIM) + i * MDIM + j];
    X[(long long)b * FEAT + f] = __float2bfloat16(v);
}

// ---------------------------------------------------------------------------
// Kernel 2: W1 fp32 [HID, FEAT] -> bf16 [HIDP, FEAT], rows >= HID zeroed
// grid: (ceil(FEAT/256), HIDP), block 256
// ---------------------------------------------------------------------------
__global__ void conv_w1_kernel(const float* __restrict__ W1,
                               __hip_bfloat16* __restrict__ W1p) {
    const int f = blockIdx.x * 256 + threadIdx.x;
    const int n = blockIdx.y;
    if (f >= FEAT) return;
    const float v = (n < HID) ? W1[(long long)n * FEAT + f] : 0.0f;
    W1p[(long long)n * FEAT + f] = __float2bfloat16(v);
}

// ---------------------------------------------------------------------------
// Kernel 3: C = X @ W1p^T fused with relu + (*W2) + row-reduce -> atomicAdd
// block 256 (4 waves, 2x2 of 64x64 subtiles), tile 128x128, BK=64
// grid: (BATCH/128, HIDP/128)
// ---------------------------------------------------------------------------
__global__ void __launch_bounds__(256, 2)
gemm_kernel(const __hip_bfloat16* __restrict__ X,
            const __hip_bfloat16* __restrict__ W1p,
            const float* __restrict__ b1,
            const float* __restrict__ W2,
            float* __restrict__ acc_out) {
    __shared__ __align__(16) __hip_bfloat16 lds_a[128 * BK];
    __shared__ __align__(16) __hip_bfloat16 lds_b[128 * BK];

    const int t    = threadIdx.x;
    const int wave = t >> 6;
    const int lane = t & 63;
    const int bm   = blockIdx.x;   // 0..31
    const int bn   = blockIdx.y;   // 0..12
    const int wm   = wave >> 1;    // 0..1
    const int wn   = wave & 1;     // 0..1

    f32x4 acc[4][4];
#pragma unroll
    for (int i = 0; i < 4; ++i)
#pragma unroll
        for (int j = 0; j < 4; ++j)
            acc[i][j] = (f32x4){0.f, 0.f, 0.f, 0.f};

    // staging: chunk c = s*256 + t; global row = c>>3, 16B col chunk = c&7
    const __hip_bfloat16* gA =
        X + (long long)(bm * 128 + (t >> 3)) * FEAT + (t & 7) * 8;
    const __hip_bfloat16* gB =
        W1p + (long long)(bn * 128 + (t >> 3)) * FEAT + (t & 7) * 8;
    // wave-uniform LDS bases (elements); lane lands at base + lane*16B
    __hip_bfloat16* lA = lds_a + wave * 512;
    __hip_bfloat16* lB = lds_b + wave * 512;

    const int lr = lane & 15;   // A row / B col within 16-tile
    const int lq = lane >> 4;   // k-quad

    for (int kt = 0; kt < FEAT / BK; ++kt) {
#pragma unroll
        for (int s = 0; s < 4; ++s) {
            gload_lds16(gA + (long long)s * 32 * FEAT, lA + s * 2048);
            gload_lds16(gB + (long long)s * 32 * FEAT, lB + s * 2048);
        }
        gA += BK;
        gB += BK;
        __syncthreads();

#pragma unroll
        for (int ks = 0; ks < 2; ++ks) {
            bf16x8 af[4], bfr[4];
#pragma unroll
            for (int i = 0; i < 4; ++i) {
                af[i]  = *(const bf16x8*)&lds_a[(wm * 64 + i * 16 + lr) * BK + ks * 32 + lq * 8];
                bfr[i] = *(const bf16x8*)&lds_b[(wn * 64 + i * 16 + lr) * BK + ks * 32 + lq * 8];
            }
#pragma unroll
            for (int i = 0; i < 4; ++i)
#pragma unroll
                for (int j = 0; j < 4; ++j)
                    acc[i][j] = __builtin_amdgcn_mfma_f32_16x16x32_bf16(
                        af[i], bfr[j], acc[i][j], 0, 0, 0);
        }
        __syncthreads();
    }

    // Epilogue: h = relu(c + b1[n]); partial = h * W2[n]; reduce over this
    // block's 128 n-columns per batch row; atomicAdd into acc_out[m].
    float b1v[4], w2v[4];
#pragma unroll
    for (int j = 0; j < 4; ++j) {
        const int n = bn * 128 + wn * 64 + j * 16 + lr;
        b1v[j] = (n < HID) ? b1[n] : 0.0f;
        w2v[j] = (n < HID) ? W2[n] : 0.0f;
    }
#pragma unroll
    for (int i = 0; i < 4; ++i) {
#pragma unroll
        for (int r = 0; r < 4; ++r) {
            float sum = 0.0f;
#pragma unroll
            for (int j = 0; j < 4; ++j) {
                float h = acc[i][j][r] + b1v[j];
                h = fmaxf(h, 0.0f);
                sum += h * w2v[j];
            }
            // reduce across the 16 lanes of this quad (same batch row)
            sum += __shfl_xor(sum, 1);
            sum += __shfl_xor(sum, 2);
            sum += __shfl_xor(sum, 4);
            sum += __shfl_xor(sum, 8);
            if (lr == 0) {
                const int m = bm * 128 + wm * 64 + i * 16 + lq * 4 + r;
                atomicAdd(&acc_out[m], sum);
            }
        }
    }
}

// ---------------------------------------------------------------------------
// Kernel 4: out[b] = sigmoid(acc[b] + b2)
// ---------------------------------------------------------------------------
__global__ void sigmoid_kernel(const float* __restrict__ acc,
                               const float* __restrict__ b2,
                               float* __restrict__ out) {
    const int i = blockIdx.x * 256 + threadIdx.x;
    if (i < BATCH) {
        const float z = acc[i] + b2[0];
        out[i] = 1.0f / (1.0f + expf(-z));
    }
}

extern "C" void kernel_launch(void* const* d_in, const int* in_sizes, int n_in,
                              void* d_out, int out_size, void* d_ws, size_t ws_size,
                              hipStream_t stream) {
    const float* sim = (const float*)d_in[0];
    const float* W1  = (const float*)d_in[1];
    const float* b1  = (const float*)d_in[2];
    const float* W2  = (const float*)d_in[3];
    const float* b2  = (const float*)d_in[4];
    float* out = (float*)d_out;

    char* ws = (char*)d_ws;
    __hip_bfloat16* X   = (__hip_bfloat16*)ws;                        // 67,633,152 B
    __hip_bfloat16* W1p = (__hip_bfloat16*)(ws + 67633152LL);         // 27,475,968 B
    float*          accb = (float*)(ws + 67633152LL + 27475968LL);    // 16,384 B

    hipMemsetAsync(accb, 0, BATCH * sizeof(float), stream);

    {
        dim3 grid((FEAT + 255) / 256, BATCH);
        pack_x_kernel<<<grid, 256, 0, stream>>>(sim, X);
    }
    {
        dim3 grid((FEAT + 255) / 256, HIDP);
        conv_w1_kernel<<<grid, 256, 0, stream>>>(W1, W1p);
    }
    {
        dim3 grid(BATCH / 128, HIDP / 128);
        gemm_kernel<<<grid, 256, 0, stream>>>(X, W1p, b1, W2, accb);
    }
    sigmoid_kernel<<<(BATCH + 255) / 256, 256, 0, stream>>>(accb, b2, out);
}

// Round 2
// 563.899 us; speedup vs baseline: 1.1701x; 1.1701x over previous
//
#include <hip/hip_runtime.h>
#include <hip/hip_bf16.h>
#include <math.h>

#define MDIM  128
#define FEAT  8256      // 128*129/2
#define HID   1651
#define HIDP  1664      // 13*128, zero-padded
#define BATCH 4096
#define BK    64
#define KT_TOTAL 129    // FEAT / BK
#define NZ    4
#define KT_PER 32       // z<3: 32 iters, z=3: 33 iters

using f32x4  = __attribute__((ext_vector_type(4))) float;
using bf16x8 = __attribute__((ext_vector_type(8))) __bf16;

__device__ __forceinline__ void gload_lds16(const void* g, void* l) {
    __builtin_amdgcn_global_load_lds(
        (const __attribute__((address_space(1))) void*)g,
        (__attribute__((address_space(3))) void*)l,
        16, 0, 0);
}

__device__ __forceinline__ int row_off(int i) { return (i * (257 - i)) >> 1; }

// ---------------------------------------------------------------------------
// Kernel 1: gather triu(sim) -> X bf16 [BATCH, FEAT]
// Output-aligned: each thread produces 8 consecutive f (one 16B bf16x8 store).
// grid-stride 1D over BATCH * (FEAT/8) work items.
// ---------------------------------------------------------------------------
__global__ void pack_x_kernel(const float* __restrict__ sim,
                              __hip_bfloat16* __restrict__ X) {
    const int NW = FEAT / 8;  // 1032
    const int gid = blockIdx.x * 256 + threadIdx.x;
    if (gid >= BATCH * NW) return;
    const int b  = gid / NW;
    const int w  = gid - b * NW;
    const int f0 = w * 8;

    // row i such that row_off(i) <= f0 < row_off(i+1)
    int i = (int)((257.0f - sqrtf(66049.0f - 8.0f * (float)f0)) * 0.5f);
    i = i < 0 ? 0 : (i > 127 ? 127 : i);
    while (i < 127 && row_off(i + 1) <= f0) ++i;
    while (i > 0 && row_off(i) > f0) --i;

    const float* srow = sim + ((long long)b << 14);
    int j = i + (f0 - row_off(i));
    __align__(16) __hip_bfloat16 tmp[8];
#pragma unroll
    for (int e = 0; e < 8; ++e) {
        if (j > 127) { ++i; j = i; }   // advance to next triu row
        tmp[e] = __float2bfloat16(srow[i * MDIM + j]);
        ++j;
    }
    *(bf16x8*)(X + (long long)b * FEAT + f0) = *(const bf16x8*)tmp;
}

// ---------------------------------------------------------------------------
// Kernel 2: W1 fp32 [HID, FEAT] -> bf16 [HIDP, FEAT], rows >= HID zeroed.
// 8 elems/thread, vectorized both sides.
// ---------------------------------------------------------------------------
__global__ void conv_w1_kernel(const float* __restrict__ W1,
                               __hip_bfloat16* __restrict__ W1p) {
    const int NW = FEAT / 8;  // 1032
    const int gid = blockIdx.x * 256 + threadIdx.x;
    if (gid >= HIDP * NW) return;
    const int n  = gid / NW;
    const int f0 = (gid - n * NW) * 8;
    __align__(16) __hip_bfloat16 tmp[8];
    if (n < HID) {
        const float* src = W1 + (long long)n * FEAT + f0;  // 16B aligned
        f32x4 a = *(const f32x4*)src;
        f32x4 c = *(const f32x4*)(src + 4);
#pragma unroll
        for (int e = 0; e < 4; ++e) {
            tmp[e]     = __float2bfloat16(a[e]);
            tmp[e + 4] = __float2bfloat16(c[e]);
        }
    } else {
#pragma unroll
        for (int e = 0; e < 8; ++e) tmp[e] = __float2bfloat16(0.0f);
    }
    *(bf16x8*)(W1p + (long long)n * FEAT + f0) = *(const bf16x8*)tmp;
}

// ---------------------------------------------------------------------------
// GEMM main loop (shared shape): 128x128 tile, BK=64, 4 waves 2x2,
// XOR-swizzled LDS to kill the 16-way bank conflicts:
//   store side (forced lane-contiguous): slot (row, ch) holds global chunk
//   ch ^ (row&7)  [achieved by swizzling the per-lane GLOBAL source chunk]
//   read side: global chunk kc lives at slot kc ^ (row&7); row&7 == lr&7.
// ---------------------------------------------------------------------------

// Kernel 3a (split-K path): partial pre-activation, atomicAdd into C fp32.
__global__ void __launch_bounds__(256, 2)
gemm_split_kernel(const __hip_bfloat16* __restrict__ X,
                  const __hip_bfloat16* __restrict__ W1p,
                  float* __restrict__ C) {
    __shared__ __align__(16) __hip_bfloat16 lds_a[128 * BK];
    __shared__ __align__(16) __hip_bfloat16 lds_b[128 * BK];

    const int t    = threadIdx.x;
    const int wave = t >> 6;
    const int lane = t & 63;
    const int bm   = blockIdx.x;
    const int bn   = blockIdx.y;
    const int z    = blockIdx.z;
    const int wm   = wave >> 1;
    const int wn   = wave & 1;
    const int lr   = lane & 15;
    const int lq   = lane >> 4;

    f32x4 acc[4][4];
#pragma unroll
    for (int i = 0; i < 4; ++i)
#pragma unroll
        for (int j = 0; j < 4; ++j)
            acc[i][j] = (f32x4){0.f, 0.f, 0.f, 0.f};

    const int kt0 = z * KT_PER;
    const int nkt = (z == NZ - 1) ? (KT_TOTAL - KT_PER * (NZ - 1)) : KT_PER;

    const int swc = (t & 7) ^ ((t >> 3) & 7);   // swizzled global source chunk
    const __hip_bfloat16* gA =
        X + (long long)(bm * 128 + (t >> 3)) * FEAT + swc * 8 + kt0 * BK;
    const __hip_bfloat16* gB =
        W1p + (long long)(bn * 128 + (t >> 3)) * FEAT + swc * 8 + kt0 * BK;
    __hip_bfloat16* lA = lds_a + wave * 512;
    __hip_bfloat16* lB = lds_b + wave * 512;

    for (int kt = 0; kt < nkt; ++kt) {
#pragma unroll
        for (int s = 0; s < 4; ++s) {
            gload_lds16(gA + (long long)s * 32 * FEAT, lA + s * 2048);
            gload_lds16(gB + (long long)s * 32 * FEAT, lB + s * 2048);
        }
        gA += BK;
        gB += BK;
        __syncthreads();

#pragma unroll
        for (int ks = 0; ks < 2; ++ks) {
            bf16x8 af[4], bfr[4];
#pragma unroll
            for (int i = 0; i < 4; ++i) {
                const int ra = wm * 64 + i * 16 + lr;
                const int rb = wn * 64 + i * 16 + lr;
                const int kc = ks * 4 + lq;
                af[i]  = *(const bf16x8*)&lds_a[(ra * 8 + (kc ^ (lr & 7))) * 8];
                bfr[i] = *(const bf16x8*)&lds_b[(rb * 8 + (kc ^ (lr & 7))) * 8];
            }
#pragma unroll
            for (int i = 0; i < 4; ++i)
#pragma unroll
                for (int j = 0; j < 4; ++j)
                    acc[i][j] = __builtin_amdgcn_mfma_f32_16x16x32_bf16(
                        af[i], bfr[j], acc[i][j], 0, 0, 0);
        }
        __syncthreads();
    }

    // accumulate partial pre-activations
#pragma unroll
    for (int i = 0; i < 4; ++i)
#pragma unroll
        for (int j = 0; j < 4; ++j)
#pragma unroll
            for (int r = 0; r < 4; ++r) {
                const int m = bm * 128 + wm * 64 + i * 16 + lq * 4 + r;
                const int n = bn * 128 + wn * 64 + j * 16 + lr;
                atomicAdd(&C[(long long)m * HIDP + n], acc[i][j][r]);
            }
}

// Kernel 3b (fallback, full-K): fused relu+W2 reduce -> atomicAdd acc_out[m].
__global__ void __launch_bounds__(256, 2)
gemm_fused_kernel(const __hip_bfloat16* __restrict__ X,
                  const __hip_bfloat16* __restrict__ W1p,
                  const float* __restrict__ b1,
                  const float* __restrict__ W2,
                  float* __restrict__ acc_out) {
    __shared__ __align__(16) __hip_bfloat16 lds_a[128 * BK];
    __shared__ __align__(16) __hip_bfloat16 lds_b[128 * BK];

    const int t    = threadIdx.x;
    const int wave = t >> 6;
    const int lane = t & 63;
    const int bm   = blockIdx.x;
    const int bn   = blockIdx.y;
    const int wm   = wave >> 1;
    const int wn   = wave & 1;
    const int lr   = lane & 15;
    const int lq   = lane >> 4;

    f32x4 acc[4][4];
#pragma unroll
    for (int i = 0; i < 4; ++i)
#pragma unroll
        for (int j = 0; j < 4; ++j)
            acc[i][j] = (f32x4){0.f, 0.f, 0.f, 0.f};

    const int swc = (t & 7) ^ ((t >> 3) & 7);
    const __hip_bfloat16* gA =
        X + (long long)(bm * 128 + (t >> 3)) * FEAT + swc * 8;
    const __hip_bfloat16* gB =
        W1p + (long long)(bn * 128 + (t >> 3)) * FEAT + swc * 8;
    __hip_bfloat16* lA = lds_a + wave * 512;
    __hip_bfloat16* lB = lds_b + wave * 512;

    for (int kt = 0; kt < KT_TOTAL; ++kt) {
#pragma unroll
        for (int s = 0; s < 4; ++s) {
            gload_lds16(gA + (long long)s * 32 * FEAT, lA + s * 2048);
            gload_lds16(gB + (long long)s * 32 * FEAT, lB + s * 2048);
        }
        gA += BK;
        gB += BK;
        __syncthreads();

#pragma unroll
        for (int ks = 0; ks < 2; ++ks) {
            bf16x8 af[4], bfr[4];
#pragma unroll
            for (int i = 0; i < 4; ++i) {
                const int ra = wm * 64 + i * 16 + lr;
                const int rb = wn * 64 + i * 16 + lr;
                const int kc = ks * 4 + lq;
                af[i]  = *(const bf16x8*)&lds_a[(ra * 8 + (kc ^ (lr & 7))) * 8];
                bfr[i] = *(const bf16x8*)&lds_b[(rb * 8 + (kc ^ (lr & 7))) * 8];
            }
#pragma unroll
            for (int i = 0; i < 4; ++i)
#pragma unroll
                for (int j = 0; j < 4; ++j)
                    acc[i][j] = __builtin_amdgcn_mfma_f32_16x16x32_bf16(
                        af[i], bfr[j], acc[i][j], 0, 0, 0);
        }
        __syncthreads();
    }

    float b1v[4], w2v[4];
#pragma unroll
    for (int j = 0; j < 4; ++j) {
        const int n = bn * 128 + wn * 64 + j * 16 + lr;
        b1v[j] = (n < HID) ? b1[n] : 0.0f;
        w2v[j] = (n < HID) ? W2[n] : 0.0f;
    }
#pragma unroll
    for (int i = 0; i < 4; ++i) {
#pragma unroll
        for (int r = 0; r < 4; ++r) {
            float sum = 0.0f;
#pragma unroll
            for (int j = 0; j < 4; ++j) {
                float h = fmaxf(acc[i][j][r] + b1v[j], 0.0f);
                sum += h * w2v[j];
            }
            sum += __shfl_xor(sum, 1);
            sum += __shfl_xor(sum, 2);
            sum += __shfl_xor(sum, 4);
            sum += __shfl_xor(sum, 8);
            if (lr == 0) {
                const int m = bm * 128 + wm * 64 + i * 16 + lq * 4 + r;
                atomicAdd(&acc_out[m], sum);
            }
        }
    }
}

// ---------------------------------------------------------------------------
// Kernel 4a (split path): out[b] = sigmoid(b2 + sum_n relu(C[b,n]+b1[n])*W2[n])
// one block per batch row
// ---------------------------------------------------------------------------
__global__ void epilogue_kernel(const float* __restrict__ C,
                                const float* __restrict__ b1,
                                const float* __restrict__ W2,
                                const float* __restrict__ b2,
                                float* __restrict__ out) {
    const int b = blockIdx.x;
    const int t = threadIdx.x;
    float sum = 0.0f;
    const f32x4* crow = (const f32x4*)(C + (long long)b * HIDP);
    for (int n4 = t; n4 < HIDP / 4; n4 += 256) {
        f32x4 c = crow[n4];
#pragma unroll
        for (int e = 0; e < 4; ++e) {
            const int n = n4 * 4 + e;
            if (n < HID) {
                const float h = fmaxf(c[e] + b1[n], 0.0f);
                sum += h * W2[n];
            }
        }
    }
    sum += __shfl_xor(sum, 1);
    sum += __shfl_xor(sum, 2);
    sum += __shfl_xor(sum, 4);
    sum += __shfl_xor(sum, 8);
    sum += __shfl_xor(sum, 16);
    sum += __shfl_xor(sum, 32);
    __shared__ float wsum[4];
    if ((t & 63) == 0) wsum[t >> 6] = sum;
    __syncthreads();
    if (t == 0) {
        const float s = wsum[0] + wsum[1] + wsum[2] + wsum[3];
        out[b] = 1.0f / (1.0f + expf(-(s + b2[0])));
    }
}

// Kernel 4b (fallback path)
__global__ void sigmoid_kernel(const float* __restrict__ acc,
                               const float* __restrict__ b2,
                               float* __restrict__ out) {
    const int i = blockIdx.x * 256 + threadIdx.x;
    if (i < BATCH) {
        const float z = acc[i] + b2[0];
        out[i] = 1.0f / (1.0f + expf(-z));
    }
}

extern "C" void kernel_launch(void* const* d_in, const int* in_sizes, int n_in,
                              void* d_out, int out_size, void* d_ws, size_t ws_size,
                              hipStream_t stream) {
    const float* sim = (const float*)d_in[0];
    const float* W1  = (const float*)d_in[1];
    const float* b1  = (const float*)d_in[2];
    const float* W2  = (const float*)d_in[3];
    const float* b2  = (const float*)d_in[4];
    float* out = (float*)d_out;

    char* ws = (char*)d_ws;
    const long long X_OFF   = 0;
    const long long W1P_OFF = 67633152LL;              // BATCH*FEAT*2
    const long long C_OFF   = W1P_OFF + 27475968LL;    // + HIDP*FEAT*2
    const long long C_BYTES = (long long)BATCH * HIDP * 4;  // 27,262,976
    __hip_bfloat16* X    = (__hip_bfloat16*)(ws + X_OFF);
    __hip_bfloat16* W1p  = (__hip_bfloat16*)(ws + W1P_OFF);
    float*          Cbuf = (float*)(ws + C_OFF);
    float*          accb = (float*)(ws + C_OFF);       // fallback reuse

    const bool use_split = ws_size >= (size_t)(C_OFF + C_BYTES);

    {
        const int total = BATCH * (FEAT / 8);
        pack_x_kernel<<<(total + 255) / 256, 256, 0, stream>>>(sim, X);
    }
    {
        const int total = HIDP * (FEAT / 8);
        conv_w1_kernel<<<(total + 255) / 256, 256, 0, stream>>>(W1, W1p);
    }

    if (use_split) {
        hipMemsetAsync(Cbuf, 0, C_BYTES, stream);
        dim3 grid(BATCH / 128, HIDP / 128, NZ);
        gemm_split_kernel<<<grid, 256, 0, stream>>>(X, W1p, Cbuf);
        epilogue_kernel<<<BATCH, 256, 0, stream>>>(Cbuf, b1, W2, b2, out);
    } else {
        hipMemsetAsync(accb, 0, BATCH * sizeof(float), stream);
        dim3 grid(BATCH / 128, HIDP / 128);
        gemm_fused_kernel<<<grid, 256, 0, stream>>>(X, W1p, b1, W2, accb);
        sigmoid_kernel<<<(BATCH + 255) / 256, 256, 0, stream>>>(accb, b2, out);
    }
}